// Round 5
// baseline (901.536 us; speedup 1.0000x reference)
//
#include <hip/hip_runtime.h>

// TGSR: y_t = y_{t-1} + M (x_t - y_{t-1}),  M = inv(L+I) = inv(B).
// R4: all plain kernel launches; Newton inverse (SM start, 5 iters);
//     G-powers; chunked scan: phase1 local scans -> carries -> phase2.
// R5: XCD-sibling swizzle + nt stores: FETCH -50MB, dur flat.
// R6: launch_bounds(512,1): no spill ever existed (AGPRs), flat.
// R7: f=32/block full-line traffic: FETCH collapsed (442->68MB), dur FLAT
//     -> phases latency-bound, not traffic-bound.
// R8: xs issue moved before MFMA cluster: flat. Scheduling theories dead.
// R9 (this round): exploit the one invariant: step time ~11us regardless of
//     content -> cut steps/phase. C=16 chunks x 8 steps: grid 256 (full CU),
//     G^8 carries (3 gsq). All 14 carry hops fused into ONE kernel (the
//     chain is block-local per (jt,f-slice)): running carry lives in LDS as
//     f16 hi/lo, f32 accumulation, 3-product GEMM per hop.

#define NITER 5
#define NPRE  3

typedef _Float16 f16x8 __attribute__((ext_vector_type(8)));
typedef _Float16 f16x4 __attribute__((ext_vector_type(4)));
typedef float    f32x4 __attribute__((ext_vector_type(4)));

#define LDSROW 520
#define ZROW   520
#define YROW   520

// ---- workspace offsets (bytes) ----
#define OFF_W      0u          // 512 f32
#define OFF_BHI    8192u       // f16 hi(B) row-major        512 KB
#define OFF_BLO    532480u     // f16 lo(B) row-major        512 KB
#define OFF_XF     1056768u    // fp32 X, col-major          1 MB
#define OFF_XRM0   2105344u    // f16(256X) row-major ping   512 KB
#define OFF_XRM1   2629632u    // pong (NITER odd -> final M here)
#define OFF_XHCM   3153920u    // f16 hi(256X) col-major
#define OFF_XLCM   3678208u    // f16 lo(256X) col-major
#define OFF_ECM    4202496u    // f16(32E) col-major
#define OFF_G0     4726784u    // G buf0: [rm_h, rm_l, cm_h, cm_l] x 512 KB = 2 MB
#define OFF_G1     6823936u    // G buf1: same layout (G^8 ends HERE)
#define OFF_STATE  8921088u    // f16 carry states [c16][jt8][f64][row512] = 8 MB
// total ~17.3 MB

#define GSUB 262144  // elements per G sub-array

__device__ __forceinline__ f32x4 MF(f16x8 a, f16x8 b, f32x4 c) {
    return __builtin_amdgcn_mfma_f32_16x16x32_f16(a, b, c, 0, 0, 0);
}
__device__ __forceinline__ unsigned long long pack4(f16x4 v) {
    union { f16x4 v; unsigned long long u; } t; t.v = v; return t.u;
}

// ---------------------------------------------------------------------------
// K1a: rowsums -> w; build B = (D+1)I - A as f16 hi/lo row-major.
// ---------------------------------------------------------------------------
__launch_bounds__(256)
__global__ void k_prep_rows(const float* __restrict__ A, unsigned char* __restrict__ wsb)
{
    float* w = (float*)(wsb + OFF_W);
    _Float16* Bhi = (_Float16*)(wsb + OFF_BHI);
    _Float16* Blo = (_Float16*)(wsb + OFF_BLO);
    const int tid = threadIdx.x;
    const int R = blockIdx.x * 16;
    __shared__ float drs[16];
    {
        int row16 = tid >> 4, seg = tid & 15;
        const float4* ap = (const float4*)&A[(size_t)(R + row16) * 512 + seg * 32];
        float p = 0.f;
        #pragma unroll
        for (int j = 0; j < 8; ++j) { float4 v = ap[j]; p += v.x + v.y + v.z + v.w; }
        #pragma unroll
        for (int off = 1; off <= 8; off <<= 1) p += __shfl_xor(p, off, 64);
        if (seg == 0) drs[row16] = p;
    }
    __syncthreads();
    if (tid < 16) w[R + tid] = 1.f / (1.f + drs[tid]);
    for (int idx = tid; idx < 8192; idx += 256) {
        int row = idx >> 9, cc = idx & 511;
        float val = ((cc == R + row) ? (drs[row] + 1.f) : 0.f) - A[(size_t)(R + row) * 512 + cc];
        _Float16 hi = (_Float16)val;
        Bhi[(size_t)(R + row) * 512 + cc] = hi;
        Blo[(size_t)(R + row) * 512 + cc] = (_Float16)(val - (float)hi);
    }
}

// ---------------------------------------------------------------------------
// K1b: X0 = W + (1-w) w^T / s  (Sherman-Morrison start).
// ---------------------------------------------------------------------------
__launch_bounds__(256)
__global__ void k_init_x(unsigned char* __restrict__ wsb)
{
    const float* w = (const float*)(wsb + OFF_W);
    float*    Xf  = (float*)(wsb + OFF_XF);
    _Float16* Xh  = (_Float16*)(wsb + OFF_XHCM);
    _Float16* Xl  = (_Float16*)(wsb + OFF_XLCM);
    _Float16* Xrm = (_Float16*)(wsb + OFF_XRM0);
    const int tid = threadIdx.x;
    const int C = blockIdx.x * 16;
    __shared__ float wl[512];
    __shared__ float red[4];
    wl[tid] = w[tid]; wl[tid + 256] = w[tid + 256];
    __syncthreads();
    float p = wl[tid] + wl[tid + 256];
    #pragma unroll
    for (int off = 32; off >= 1; off >>= 1) p += __shfl_xor(p, off, 64);
    if ((tid & 63) == 0) red[tid >> 6] = p;
    __syncthreads();
    const float s = red[0] + red[1] + red[2] + red[3];
    for (int idx = tid; idx < 8192; idx += 256) {
        int col = C + (idx >> 9), row = idx & 511;
        float wr = wl[row];
        float xv = ((row == col) ? wr : 0.f) + (1.f - wr) * wl[col] / s;
        Xf[(size_t)col * 512 + row] = xv;
        float sc = xv * 256.f;
        _Float16 h = (_Float16)sc;
        Xh[(size_t)col * 512 + row] = h;
        Xl[(size_t)col * 512 + row] = (_Float16)(sc - (float)h);
        Xrm[(size_t)row * 512 + col] = h;
    }
}

// ---------------------------------------------------------------------------
// K2: E = I - B@X   (acc = 256*(B@X); split 3-product for nit >= NPRE)
// ---------------------------------------------------------------------------
__launch_bounds__(256)
__global__ void k_newton_e(unsigned char* __restrict__ wsb, int nit)
{
    const _Float16* Bhi = (const _Float16*)(wsb + OFF_BHI);
    const _Float16* Blo = (const _Float16*)(wsb + OFF_BLO);
    const _Float16* Xh  = (const _Float16*)(wsb + OFF_XHCM);
    const _Float16* Xl  = (const _Float16*)(wsb + OFF_XLCM);
    _Float16* Ecm = (_Float16*)(wsb + OFF_ECM);

    const int tid = threadIdx.x;
    const int lane = tid & 63, w = tid >> 6, q = lane >> 4, nI = lane & 15;
    const int bx = blockIdx.x;
    const int jt = bx & 7, R = (bx >> 3) * 16;
    const int c = jt * 64 + w * 16 + nI;

    __shared__ _Float16 pan[2][16 * LDSROW];
    #pragma unroll
    for (int rep = 0; rep < 4; ++rep) {
        int idx = tid + rep * 256; int row = idx >> 6, seg = idx & 63;
        *(f16x8*)&pan[0][row * LDSROW + seg * 8] = *(const f16x8*)&Bhi[(size_t)(R + row) * 512 + seg * 8];
        *(f16x8*)&pan[1][row * LDSROW + seg * 8] = *(const f16x8*)&Blo[(size_t)(R + row) * 512 + seg * 8];
    }
    __syncthreads();

    const _Float16* xh = Xh + (size_t)c * 512;
    const _Float16* xl = Xl + (size_t)c * 512;
    f32x4 acc = {0.f, 0.f, 0.f, 0.f};
    #pragma unroll
    for (int kk = 0; kk < 16; ++kk)
        acc = MF(*(f16x8*)&pan[0][nI * LDSROW + kk * 32 + q * 8], *(const f16x8*)&xh[kk * 32 + q * 8], acc);
    if (nit >= NPRE) {
        #pragma unroll
        for (int kk = 0; kk < 16; ++kk)
            acc = MF(*(f16x8*)&pan[0][nI * LDSROW + kk * 32 + q * 8], *(const f16x8*)&xl[kk * 32 + q * 8], acc);
        #pragma unroll
        for (int kk = 0; kk < 16; ++kk)
            acc = MF(*(f16x8*)&pan[1][nI * LDSROW + kk * 32 + q * 8], *(const f16x8*)&xh[kk * 32 + q * 8], acc);
    }
    f16x4 ev;
    #pragma unroll
    for (int r4 = 0; r4 < 4; ++r4) {
        int row = R + q * 4 + r4;
        float e = ((row == c) ? 1.f : 0.f) - acc[r4] * (1.f / 256.f);
        ev[r4] = (_Float16)(e * 32.f);
    }
    *(f16x4*)&Ecm[(size_t)c * 512 + R + q * 4] = ev;
}

// ---------------------------------------------------------------------------
// K3: X += X@E   (acc = (256X)@(32E) = 8192*(X@E)); fp32 master in Xf (cm).
// ---------------------------------------------------------------------------
__launch_bounds__(256)
__global__ void k_newton_u(unsigned char* __restrict__ wsb, int nit)
{
    const _Float16* Xrm_cur = (const _Float16*)(wsb + ((nit & 1) ? OFF_XRM1 : OFF_XRM0));
    _Float16*       Xrm_nxt = (_Float16*)(wsb + ((nit & 1) ? OFF_XRM0 : OFF_XRM1));
    const _Float16* Ecm = (const _Float16*)(wsb + OFF_ECM);
    float*    Xf = (float*)(wsb + OFF_XF);
    _Float16* Xh = (_Float16*)(wsb + OFF_XHCM);
    _Float16* Xl = (_Float16*)(wsb + OFF_XLCM);

    const int tid = threadIdx.x;
    const int lane = tid & 63, w = tid >> 6, q = lane >> 4, nI = lane & 15;
    const int bx = blockIdx.x;
    const int jt = bx & 7, R = (bx >> 3) * 16;
    const int c = jt * 64 + w * 16 + nI;

    __shared__ _Float16 pan[16 * LDSROW];
    #pragma unroll
    for (int rep = 0; rep < 4; ++rep) {
        int idx = tid + rep * 256; int row = idx >> 6, seg = idx & 63;
        *(f16x8*)&pan[row * LDSROW + seg * 8] = *(const f16x8*)&Xrm_cur[(size_t)(R + row) * 512 + seg * 8];
    }
    __syncthreads();

    const _Float16* ec = Ecm + (size_t)c * 512;
    f32x4 acc = {0.f, 0.f, 0.f, 0.f};
    #pragma unroll
    for (int kk = 0; kk < 16; ++kk)
        acc = MF(*(f16x8*)&pan[nI * LDSROW + kk * 32 + q * 8], *(const f16x8*)&ec[kk * 32 + q * 8], acc);

    f32x4 xv4 = *(f32x4*)&Xf[(size_t)c * 512 + R + q * 4];
    f16x4 h4, l4;
    #pragma unroll
    for (int r4 = 0; r4 < 4; ++r4) {
        float xv = xv4[r4] + acc[r4] * (1.f / 8192.f);
        xv4[r4] = xv;
        float sc = xv * 256.f;
        h4[r4] = (_Float16)sc;
        l4[r4] = (_Float16)(sc - (float)h4[r4]);
    }
    *(f32x4*)&Xf[(size_t)c * 512 + R + q * 4] = xv4;
    *(unsigned long long*)&Xh[(size_t)c * 512 + R + q * 4] = pack4(h4);
    *(unsigned long long*)&Xl[(size_t)c * 512 + R + q * 4] = pack4(l4);
    #pragma unroll
    for (int r4 = 0; r4 < 4; ++r4) {
        int row = R + q * 4 + r4;
        union { _Float16 h; unsigned short s; } cv; cv.h = h4[r4];
        unsigned x = cv.s;
        unsigned px = (unsigned)__shfl_xor((int)x, 1, 64);
        if ((nI & 1) == 0)
            *(unsigned*)&Xrm_nxt[(size_t)row * 512 + c] = x | (px << 16);
    }
}

// ---------------------------------------------------------------------------
// K4: G = I - M  ->  G buf0 as 256*G, hi/lo, row-major + col-major.
// ---------------------------------------------------------------------------
__launch_bounds__(256)
__global__ void k_gprep(unsigned char* __restrict__ wsb)
{
    const float* Xf = (const float*)(wsb + OFF_XF);
    _Float16* G = (_Float16*)(wsb + OFF_G0);
    _Float16* Grmh = G, *Grml = G + GSUB, *Gcmh = G + 2 * GSUB, *Gcml = G + 3 * GSUB;
    const int tid = threadIdx.x;
    const int C = blockIdx.x * 16;
    for (int idx = tid; idx < 8192; idx += 256) {
        int col = C + (idx >> 9), row = idx & 511;
        float g = ((row == col) ? 1.f : 0.f) - Xf[(size_t)col * 512 + row];
        float sc = g * 256.f;
        _Float16 h = (_Float16)sc;
        _Float16 l = (_Float16)(sc - (float)h);
        Gcmh[(size_t)col * 512 + row] = h;
        Gcml[(size_t)col * 512 + row] = l;
        Grmh[(size_t)row * 512 + col] = h;
        Grml[(size_t)row * 512 + col] = l;
    }
}

// ---------------------------------------------------------------------------
// K5: G2 = G@G (hi/lo split, 3 products). In: 256*G, out: 256*G^2.
// ---------------------------------------------------------------------------
__launch_bounds__(256)
__global__ void k_gsq(const _Float16* __restrict__ Gin, _Float16* __restrict__ Gout)
{
    const _Float16* rmh = Gin, *rml = Gin + GSUB, *cmh = Gin + 2 * GSUB, *cml = Gin + 3 * GSUB;
    _Float16* ormh = Gout; _Float16* orml = Gout + GSUB;
    _Float16* ocmh = Gout + 2 * GSUB; _Float16* ocml = Gout + 3 * GSUB;

    const int tid = threadIdx.x;
    const int lane = tid & 63, w = tid >> 6, q = lane >> 4, nI = lane & 15;
    const int bx = blockIdx.x;
    const int jt = bx & 7, R = (bx >> 3) * 16;
    const int c = jt * 64 + w * 16 + nI;

    __shared__ _Float16 pan[2][16 * LDSROW];
    #pragma unroll
    for (int rep = 0; rep < 4; ++rep) {
        int idx = tid + rep * 256; int row = idx >> 6, seg = idx & 63;
        *(f16x8*)&pan[0][row * LDSROW + seg * 8] = *(const f16x8*)&rmh[(size_t)(R + row) * 512 + seg * 8];
        *(f16x8*)&pan[1][row * LDSROW + seg * 8] = *(const f16x8*)&rml[(size_t)(R + row) * 512 + seg * 8];
    }
    __syncthreads();

    const _Float16* bh = cmh + (size_t)c * 512;
    const _Float16* bl = cml + (size_t)c * 512;
    f32x4 acc = {0.f, 0.f, 0.f, 0.f};
    #pragma unroll
    for (int kk = 0; kk < 16; ++kk) {
        f16x8 ah = *(f16x8*)&pan[0][nI * LDSROW + kk * 32 + q * 8];
        f16x8 al = *(f16x8*)&pan[1][nI * LDSROW + kk * 32 + q * 8];
        f16x8 vh = *(const f16x8*)&bh[kk * 32 + q * 8];
        f16x8 vl = *(const f16x8*)&bl[kk * 32 + q * 8];
        acc = MF(ah, vh, acc);
        acc = MF(ah, vl, acc);
        acc = MF(al, vh, acc);
    }
    f16x4 h4, l4;
    #pragma unroll
    for (int r4 = 0; r4 < 4; ++r4) {
        float v = acc[r4] * (1.f / 256.f);   // 256*G^2
        h4[r4] = (_Float16)v;
        l4[r4] = (_Float16)(v - (float)h4[r4]);
    }
    *(unsigned long long*)&ocmh[(size_t)c * 512 + R + q * 4] = pack4(h4);
    *(unsigned long long*)&ocml[(size_t)c * 512 + R + q * 4] = pack4(l4);
    #pragma unroll
    for (int r4 = 0; r4 < 4; ++r4) {
        int row = R + q * 4 + r4;
        union { _Float16 h; unsigned short s; } cv, cl; cv.h = h4[r4]; cl.h = l4[r4];
        unsigned xh = cv.s, xl = cl.s;
        unsigned pxh = (unsigned)__shfl_xor((int)xh, 1, 64);
        unsigned pxl = (unsigned)__shfl_xor((int)xl, 1, 64);
        if ((nI & 1) == 0) {
            *(unsigned*)&ormh[(size_t)row * 512 + c] = xh | (pxh << 16);
            *(unsigned*)&orml[(size_t)row * 512 + c] = xl | (pxl << 16);
        }
    }
}

// ---------------------------------------------------------------------------
// K6: phase-1 local chunk scan (8 steps, zero init), emit end state (f16 cm).
// 256 blocks x 512 threads: bx = cg*128 + ch*8 + jt; cg in {0,1} (f-half),
// ch in 0..15 (chunk of 8 steps), jt = batch. f-width 32 per block.
// ---------------------------------------------------------------------------
__launch_bounds__(512, 1)
__global__ void k_phase1(const float* __restrict__ xs, unsigned char* __restrict__ wsb)
{
    const _Float16* Mrm = (const _Float16*)(wsb + OFF_XRM1);   // NITER odd
    _Float16* state = (_Float16*)(wsb + OFF_STATE);

    const int tid = threadIdx.x;
    const int lane = tid & 63, wv = tid >> 6, q = lane >> 4, nI = lane & 15;
    const int bx = blockIdx.x;
    const int cg = bx >> 7, ch = (bx >> 3) & 15, jt = bx & 7;
    const int rowbase = wv * 64;
    const int f0 = cg * 32 + nI;          // cf=1 adds +16

    __shared__ _Float16 Z[2][32 * ZROW];

    f16x8 a0[16], a1[16];
    #pragma unroll
    for (int kk = 0; kk < 16; ++kk)
        a0[kk] = *(const f16x8*)&Mrm[(size_t)(rowbase + nI) * 512 + kk * 32 + q * 8];
    #pragma unroll
    for (int kk = 0; kk < 16; ++kk)
        a1[kk] = *(const f16x8*)&Mrm[(size_t)(rowbase + 16 + nI) * 512 + kk * 32 + q * 8];
    const _Float16* m2 = &Mrm[(size_t)(rowbase + 32 + nI) * 512];
    const _Float16* m3 = &Mrm[(size_t)(rowbase + 48 + nI) * 512];

    // acc[T][cf] = 256 * Y   (persistent across steps; MFMA C-in = C-out)
    f32x4 acc[4][2];
    #pragma unroll
    for (int T = 0; T < 4; ++T)
        #pragma unroll
        for (int cf = 0; cf < 2; ++cf)
            acc[T][cf] = (f32x4){0.f, 0.f, 0.f, 0.f};

    float xn[4][2][4];
    const int tg0 = ch * 8;

    {   // preamble: build Z[0] from x_0
        const size_t b0 = ((size_t)(jt * 128 + tg0) * 512) * 64 + f0;
        #pragma unroll
        for (int T = 0; T < 4; ++T)
            #pragma unroll
            for (int cf = 0; cf < 2; ++cf) {
                f16x4 zv;
                #pragma unroll
                for (int r4 = 0; r4 < 4; ++r4)
                    zv[r4] = (_Float16)xs[b0 + cf * 16 + (size_t)(rowbase + T * 16 + q * 4 + r4) * 64];
                *(f16x4*)&Z[0][(cf * 16 + nI) * ZROW + rowbase + T * 16 + q * 4] = zv;
            }
    }
    __syncthreads();

    for (int t = 0; t < 8; ++t) {
        if (t < 7) {
            const size_t bn = ((size_t)(jt * 128 + tg0 + t + 1) * 512) * 64 + f0;
            #pragma unroll
            for (int T = 0; T < 4; ++T)
                #pragma unroll
                for (int cf = 0; cf < 2; ++cf)
                    #pragma unroll
                    for (int r4 = 0; r4 < 4; ++r4)
                        xn[T][cf][r4] = xs[bn + cf * 16 + (size_t)(rowbase + T * 16 + q * 4 + r4) * 64];
        }

        const _Float16* zbA = &Z[t & 1][nI * ZROW];
        const _Float16* zbB = &Z[t & 1][(16 + nI) * ZROW];
        #pragma unroll
        for (int kk = 0; kk < 16; ++kk) {
            f16x8 bA = *(const f16x8*)&zbA[kk * 32 + q * 8];
            f16x8 bB = *(const f16x8*)&zbB[kk * 32 + q * 8];
            f16x8 v2 = *(const f16x8*)&m2[kk * 32 + q * 8];
            f16x8 v3 = *(const f16x8*)&m3[kk * 32 + q * 8];
            acc[0][0] = MF(a0[kk], bA, acc[0][0]);
            acc[0][1] = MF(a0[kk], bB, acc[0][1]);
            acc[1][0] = MF(a1[kk], bA, acc[1][0]);
            acc[1][1] = MF(a1[kk], bB, acc[1][1]);
            acc[2][0] = MF(v2,     bA, acc[2][0]);
            acc[2][1] = MF(v2,     bB, acc[2][1]);
            acc[3][0] = MF(v3,     bA, acc[3][0]);
            acc[3][1] = MF(v3,     bB, acc[3][1]);
        }

        if (t < 7) {
            #pragma unroll
            for (int T = 0; T < 4; ++T)
                #pragma unroll
                for (int cf = 0; cf < 2; ++cf) {
                    f16x4 zv;
                    #pragma unroll
                    for (int r4 = 0; r4 < 4; ++r4)
                        zv[r4] = (_Float16)(xn[T][cf][r4] - acc[T][cf][r4] * (1.f / 256.f));
                    *(f16x4*)&Z[(t + 1) & 1][(cf * 16 + nI) * ZROW + rowbase + T * 16 + q * 4] = zv;
                }
            __syncthreads();
        }
    }

    #pragma unroll
    for (int cf = 0; cf < 2; ++cf) {
        _Float16* st = state + ((size_t)(ch * 8 + jt) * 64 + f0 + cf * 16) * 512;
        #pragma unroll
        for (int T = 0; T < 4; ++T) {
            f16x4 sv;
            #pragma unroll
            for (int r4 = 0; r4 < 4; ++r4) sv[r4] = (_Float16)(acc[T][cf][r4] * (1.f / 256.f));
            *(unsigned long long*)&st[rowbase + T * 16 + q * 4] = pack4(sv);
        }
    }
}

// ---------------------------------------------------------------------------
// K7: ALL carry hops fused: for c = 1..14: state[c] = E_c + G8 @ y_{c-1}.
// The chain is block-local: block owns (jt, 16-wide f-slice); running carry
// y lives in LDS as f16 hi/lo (f32 accumulation, 3-product GEMM per hop).
// 32 blocks x 512 threads: jt = bx>>2, cg = bx&3.
// ---------------------------------------------------------------------------
__launch_bounds__(512, 1)
__global__ void k_carry_all(unsigned char* __restrict__ wsb)
{
    const _Float16* G8h = (const _Float16*)(wsb + OFF_G1);           // rm hi (256*G8)
    const _Float16* G8l = (const _Float16*)(wsb + OFF_G1) + GSUB;    // rm lo
    _Float16* state = (_Float16*)(wsb + OFF_STATE);

    const int tid = threadIdx.x;
    const int lane = tid & 63, wv = tid >> 6, q = lane >> 4, nI = lane & 15;
    const int bx = blockIdx.x;
    const int jt = bx >> 2, cg = bx & 3;
    const int rowbase = wv * 64;
    const int f = cg * 16 + nI;

    __shared__ _Float16 Yh[16 * YROW];
    __shared__ _Float16 Yl[16 * YROW];

    {   // init running carry from chunk-0 end state (pure f16 -> lo = 0)
        const _Float16* st0 = state + ((size_t)(0 * 8 + jt) * 64 + f) * 512;
        #pragma unroll
        for (int T = 0; T < 4; ++T) {
            f16x4 sv = *(const f16x4*)&st0[rowbase + T * 16 + q * 4];
            *(unsigned long long*)&Yh[nI * YROW + rowbase + T * 16 + q * 4] = pack4(sv);
            f16x4 z4 = {(_Float16)0.f, (_Float16)0.f, (_Float16)0.f, (_Float16)0.f};
            *(unsigned long long*)&Yl[nI * YROW + rowbase + T * 16 + q * 4] = pack4(z4);
        }
    }
    __syncthreads();

    for (int c = 1; c <= 14; ++c) {
        f32x4 acc[4] = {{0,0,0,0},{0,0,0,0},{0,0,0,0},{0,0,0,0}};
        #pragma unroll 4
        for (int kk = 0; kk < 16; ++kk) {
            f16x8 bh = *(const f16x8*)&Yh[nI * YROW + kk * 32 + q * 8];
            f16x8 bl = *(const f16x8*)&Yl[nI * YROW + kk * 32 + q * 8];
            #pragma unroll
            for (int T = 0; T < 4; ++T) {
                f16x8 ah = *(const f16x8*)&G8h[(size_t)(rowbase + T * 16 + nI) * 512 + kk * 32 + q * 8];
                f16x8 al = *(const f16x8*)&G8l[(size_t)(rowbase + T * 16 + nI) * 512 + kk * 32 + q * 8];
                acc[T] = MF(ah, bh, acc[T]);
                acc[T] = MF(ah, bl, acc[T]);
                acc[T] = MF(al, bh, acc[T]);
            }
        }
        __syncthreads();   // all Y reads done before overwrite

        _Float16* stc = state + ((size_t)(c * 8 + jt) * 64 + f) * 512;
        #pragma unroll
        for (int T = 0; T < 4; ++T) {
            f16x4 e4 = *(const f16x4*)&stc[rowbase + T * 16 + q * 4];
            f16x4 h4, l4;
            #pragma unroll
            for (int r4 = 0; r4 < 4; ++r4) {
                float y = (float)e4[r4] + acc[T][r4] * (1.f / 256.f);
                h4[r4] = (_Float16)y;
                l4[r4] = (_Float16)(y - (float)h4[r4]);
            }
            *(unsigned long long*)&stc[rowbase + T * 16 + q * 4] = pack4(h4);   // phase2 reads f16
            *(unsigned long long*)&Yh[nI * YROW + rowbase + T * 16 + q * 4] = pack4(h4);
            *(unsigned long long*)&Yl[nI * YROW + rowbase + T * 16 + q * 4] = pack4(l4);
        }
        __syncthreads();
    }
}

// ---------------------------------------------------------------------------
// K8: phase-2 final chunk scan (8 steps) with carry-in; writes out (nt).
// ---------------------------------------------------------------------------
__launch_bounds__(512, 1)
__global__ void k_phase2(const float* __restrict__ xs, unsigned char* __restrict__ wsb,
                         float* __restrict__ out)
{
    const _Float16* Mrm = (const _Float16*)(wsb + OFF_XRM1);
    const _Float16* state = (const _Float16*)(wsb + OFF_STATE);

    const int tid = threadIdx.x;
    const int lane = tid & 63, wv = tid >> 6, q = lane >> 4, nI = lane & 15;
    const int bx = blockIdx.x;
    const int cg = bx >> 7, ch = (bx >> 3) & 15, jt = bx & 7;
    const int rowbase = wv * 64;
    const int f0 = cg * 32 + nI;

    __shared__ _Float16 Z[2][32 * ZROW];

    f16x8 a0[16], a1[16];
    #pragma unroll
    for (int kk = 0; kk < 16; ++kk)
        a0[kk] = *(const f16x8*)&Mrm[(size_t)(rowbase + nI) * 512 + kk * 32 + q * 8];
    #pragma unroll
    for (int kk = 0; kk < 16; ++kk)
        a1[kk] = *(const f16x8*)&Mrm[(size_t)(rowbase + 16 + nI) * 512 + kk * 32 + q * 8];
    const _Float16* m2 = &Mrm[(size_t)(rowbase + 32 + nI) * 512];
    const _Float16* m3 = &Mrm[(size_t)(rowbase + 48 + nI) * 512];

    // acc = 256 * Y, initialized from carry state (or 0 for chunk 0)
    f32x4 acc[4][2];
    if (ch == 0) {
        #pragma unroll
        for (int T = 0; T < 4; ++T)
            #pragma unroll
            for (int cf = 0; cf < 2; ++cf)
                acc[T][cf] = (f32x4){0.f, 0.f, 0.f, 0.f};
    } else {
        #pragma unroll
        for (int cf = 0; cf < 2; ++cf) {
            const _Float16* st = state + ((size_t)((ch - 1) * 8 + jt) * 64 + f0 + cf * 16) * 512;
            #pragma unroll
            for (int T = 0; T < 4; ++T) {
                f16x4 sv = *(const f16x4*)&st[rowbase + T * 16 + q * 4];
                #pragma unroll
                for (int r4 = 0; r4 < 4; ++r4) acc[T][cf][r4] = 256.f * (float)sv[r4];
            }
        }
    }

    float xn[4][2][4];
    const int tg0 = ch * 8;
    {   // preamble: Z[0] = x_0 - Y_carry
        const size_t b0 = ((size_t)(jt * 128 + tg0) * 512) * 64 + f0;
        #pragma unroll
        for (int T = 0; T < 4; ++T)
            #pragma unroll
            for (int cf = 0; cf < 2; ++cf) {
                f16x4 zv;
                #pragma unroll
                for (int r4 = 0; r4 < 4; ++r4) {
                    float xv = xs[b0 + cf * 16 + (size_t)(rowbase + T * 16 + q * 4 + r4) * 64];
                    zv[r4] = (_Float16)(xv - acc[T][cf][r4] * (1.f / 256.f));
                }
                *(f16x4*)&Z[0][(cf * 16 + nI) * ZROW + rowbase + T * 16 + q * 4] = zv;
            }
    }
    __syncthreads();

    for (int t = 0; t < 8; ++t) {
        if (t < 7) {
            const size_t bn = ((size_t)(jt * 128 + tg0 + t + 1) * 512) * 64 + f0;
            #pragma unroll
            for (int T = 0; T < 4; ++T)
                #pragma unroll
                for (int cf = 0; cf < 2; ++cf)
                    #pragma unroll
                    for (int r4 = 0; r4 < 4; ++r4)
                        xn[T][cf][r4] = xs[bn + cf * 16 + (size_t)(rowbase + T * 16 + q * 4 + r4) * 64];
        }

        const _Float16* zbA = &Z[t & 1][nI * ZROW];
        const _Float16* zbB = &Z[t & 1][(16 + nI) * ZROW];
        #pragma unroll
        for (int kk = 0; kk < 16; ++kk) {
            f16x8 bA = *(const f16x8*)&zbA[kk * 32 + q * 8];
            f16x8 bB = *(const f16x8*)&zbB[kk * 32 + q * 8];
            f16x8 v2 = *(const f16x8*)&m2[kk * 32 + q * 8];
            f16x8 v3 = *(const f16x8*)&m3[kk * 32 + q * 8];
            acc[0][0] = MF(a0[kk], bA, acc[0][0]);
            acc[0][1] = MF(a0[kk], bB, acc[0][1]);
            acc[1][0] = MF(a1[kk], bA, acc[1][0]);
            acc[1][1] = MF(a1[kk], bB, acc[1][1]);
            acc[2][0] = MF(v2,     bA, acc[2][0]);
            acc[2][1] = MF(v2,     bB, acc[2][1]);
            acc[3][0] = MF(v3,     bA, acc[3][0]);
            acc[3][1] = MF(v3,     bB, acc[3][1]);
        }

        const size_t base = ((size_t)(jt * 128 + tg0 + t) * 512) * 64 + f0;
        #pragma unroll
        for (int T = 0; T < 4; ++T)
            #pragma unroll
            for (int cf = 0; cf < 2; ++cf)
                #pragma unroll
                for (int r4 = 0; r4 < 4; ++r4)
                    __builtin_nontemporal_store(acc[T][cf][r4] * (1.f / 256.f),
                        &out[base + cf * 16 + (size_t)(rowbase + T * 16 + q * 4 + r4) * 64]);

        if (t < 7) {
            #pragma unroll
            for (int T = 0; T < 4; ++T)
                #pragma unroll
                for (int cf = 0; cf < 2; ++cf) {
                    f16x4 zv;
                    #pragma unroll
                    for (int r4 = 0; r4 < 4; ++r4)
                        zv[r4] = (_Float16)(xn[T][cf][r4] - acc[T][cf][r4] * (1.f / 256.f));
                    *(f16x4*)&Z[(t + 1) & 1][(cf * 16 + nI) * ZROW + rowbase + T * 16 + q * 4] = zv;
                }
            __syncthreads();
        }
    }
}

extern "C" void kernel_launch(void* const* d_in, const int* in_sizes, int n_in,
                              void* d_out, int out_size, void* d_ws, size_t ws_size,
                              hipStream_t stream)
{
    const float* xs = (const float*)d_in[0];   // [8,128,512,64] fp32
    const float* A  = (const float*)d_in[1];   // [1,512,512] fp32
    float* out = (float*)d_out;                // [8,128,512,64] fp32
    unsigned char* ws = (unsigned char*)d_ws;  // ~17.3 MB used

    k_prep_rows<<<dim3(32), dim3(256), 0, stream>>>(A, ws);
    k_init_x<<<dim3(32), dim3(256), 0, stream>>>(ws);

    for (int nit = 0; nit < NITER; ++nit) {
        k_newton_e<<<dim3(256), dim3(256), 0, stream>>>(ws, nit);
        k_newton_u<<<dim3(256), dim3(256), 0, stream>>>(ws, nit);
    }

    k_gprep<<<dim3(32), dim3(256), 0, stream>>>(ws);
    _Float16* G0 = (_Float16*)(ws + OFF_G0);
    _Float16* G1 = (_Float16*)(ws + OFF_G1);
    k_gsq<<<dim3(256), dim3(256), 0, stream>>>(G0, G1);   // G^2 -> buf1
    k_gsq<<<dim3(256), dim3(256), 0, stream>>>(G1, G0);   // G^4 -> buf0
    k_gsq<<<dim3(256), dim3(256), 0, stream>>>(G0, G1);   // G^8 -> buf1

    k_phase1<<<dim3(256), dim3(512), 0, stream>>>(xs, ws);
    k_carry_all<<<dim3(32), dim3(512), 0, stream>>>(ws);
    k_phase2<<<dim3(256), dim3(512), 0, stream>>>(xs, ws, out);
}

// Round 6
// 561.600 us; speedup vs baseline: 1.6053x; 1.6053x over previous
//
#include <hip/hip_runtime.h>

// TGSR: y_t = y_{t-1} + M (x_t - y_{t-1}),  M = inv(L+I) = inv(B).
// R4..R8: see git history. Key measured facts:
//  - Phase step time ~11us, invariant to traffic/f-width/scheduling.
//  - R9: fused 32-block carry = 417us (30us/hop). Diagnosis: L2-resident
//    matrix streaming runs at ~14 B/cy/CU (latency x queue-depth: 2 waves/
//    SIMD x 32 outstanding 16B loads / ~300cy L2 latency). Explains BOTH the
//    carry hops (1MB G8/block-hop -> 30us) and the phase step (256KB m2/m3
//    per CU-step -> ~7.5us of the 11).
// R10 (this round):
//  - Carry: 14 plain-launch hop GEMMs, 256 blocks each (16 rows x 64f x jt),
//    G8 row-panel staged in LDS, k split across wave halves, y hi/lo carried
//    in HBM (phase1 emits hi+lo, phase2 reads hi+lo). ~6us/hop expected.
//  - Phases: hold first 8 kk-slices of tile-2 in registers (+32 regs ->
//    ~244/wave, within the 256 cap at 2 waves/SIMD); stream 24KB not 32KB
//    per wave-step.

#define NITER 5
#define NPRE  3

typedef _Float16 f16x8 __attribute__((ext_vector_type(8)));
typedef _Float16 f16x4 __attribute__((ext_vector_type(4)));
typedef float    f32x4 __attribute__((ext_vector_type(4)));

#define LDSROW 520
#define ZROW   520
#define GROW   520

// ---- workspace offsets (bytes) ----
#define OFF_W      0u          // 512 f32
#define OFF_BHI    8192u       // f16 hi(B) row-major        512 KB
#define OFF_BLO    532480u     // f16 lo(B) row-major        512 KB
#define OFF_XF     1056768u    // fp32 X, col-major          1 MB
#define OFF_XRM0   2105344u    // f16(256X) row-major ping   512 KB
#define OFF_XRM1   2629632u    // pong (NITER odd -> final M here)
#define OFF_XHCM   3153920u    // f16 hi(256X) col-major
#define OFF_XLCM   3678208u    // f16 lo(256X) col-major
#define OFF_ECM    4202496u    // f16(32E) col-major
#define OFF_G0     4726784u    // G buf0: [rm_h, rm_l, cm_h, cm_l] x 512 KB = 2 MB
#define OFF_G1     6823936u    // G buf1: same layout (G^8 ends HERE)
#define OFF_STH    8921088u    // f16 HI carry states [c16][jt8][f64][row512] = 8 MB
#define OFF_STL    17309696u   // f16 LO carry states, same layout = 8 MB
// total ~25.7 MB

#define GSUB 262144  // elements per G sub-array

__device__ __forceinline__ f32x4 MF(f16x8 a, f16x8 b, f32x4 c) {
    return __builtin_amdgcn_mfma_f32_16x16x32_f16(a, b, c, 0, 0, 0);
}
__device__ __forceinline__ unsigned long long pack4(f16x4 v) {
    union { f16x4 v; unsigned long long u; } t; t.v = v; return t.u;
}

// ---------------------------------------------------------------------------
// K1a: rowsums -> w; build B = (D+1)I - A as f16 hi/lo row-major.
// ---------------------------------------------------------------------------
__launch_bounds__(256)
__global__ void k_prep_rows(const float* __restrict__ A, unsigned char* __restrict__ wsb)
{
    float* w = (float*)(wsb + OFF_W);
    _Float16* Bhi = (_Float16*)(wsb + OFF_BHI);
    _Float16* Blo = (_Float16*)(wsb + OFF_BLO);
    const int tid = threadIdx.x;
    const int R = blockIdx.x * 16;
    __shared__ float drs[16];
    {
        int row16 = tid >> 4, seg = tid & 15;
        const float4* ap = (const float4*)&A[(size_t)(R + row16) * 512 + seg * 32];
        float p = 0.f;
        #pragma unroll
        for (int j = 0; j < 8; ++j) { float4 v = ap[j]; p += v.x + v.y + v.z + v.w; }
        #pragma unroll
        for (int off = 1; off <= 8; off <<= 1) p += __shfl_xor(p, off, 64);
        if (seg == 0) drs[row16] = p;
    }
    __syncthreads();
    if (tid < 16) w[R + tid] = 1.f / (1.f + drs[tid]);
    for (int idx = tid; idx < 8192; idx += 256) {
        int row = idx >> 9, cc = idx & 511;
        float val = ((cc == R + row) ? (drs[row] + 1.f) : 0.f) - A[(size_t)(R + row) * 512 + cc];
        _Float16 hi = (_Float16)val;
        Bhi[(size_t)(R + row) * 512 + cc] = hi;
        Blo[(size_t)(R + row) * 512 + cc] = (_Float16)(val - (float)hi);
    }
}

// ---------------------------------------------------------------------------
// K1b: X0 = W + (1-w) w^T / s  (Sherman-Morrison start).
// ---------------------------------------------------------------------------
__launch_bounds__(256)
__global__ void k_init_x(unsigned char* __restrict__ wsb)
{
    const float* w = (const float*)(wsb + OFF_W);
    float*    Xf  = (float*)(wsb + OFF_XF);
    _Float16* Xh  = (_Float16*)(wsb + OFF_XHCM);
    _Float16* Xl  = (_Float16*)(wsb + OFF_XLCM);
    _Float16* Xrm = (_Float16*)(wsb + OFF_XRM0);
    const int tid = threadIdx.x;
    const int C = blockIdx.x * 16;
    __shared__ float wl[512];
    __shared__ float red[4];
    wl[tid] = w[tid]; wl[tid + 256] = w[tid + 256];
    __syncthreads();
    float p = wl[tid] + wl[tid + 256];
    #pragma unroll
    for (int off = 32; off >= 1; off >>= 1) p += __shfl_xor(p, off, 64);
    if ((tid & 63) == 0) red[tid >> 6] = p;
    __syncthreads();
    const float s = red[0] + red[1] + red[2] + red[3];
    for (int idx = tid; idx < 8192; idx += 256) {
        int col = C + (idx >> 9), row = idx & 511;
        float wr = wl[row];
        float xv = ((row == col) ? wr : 0.f) + (1.f - wr) * wl[col] / s;
        Xf[(size_t)col * 512 + row] = xv;
        float sc = xv * 256.f;
        _Float16 h = (_Float16)sc;
        Xh[(size_t)col * 512 + row] = h;
        Xl[(size_t)col * 512 + row] = (_Float16)(sc - (float)h);
        Xrm[(size_t)row * 512 + col] = h;
    }
}

// ---------------------------------------------------------------------------
// K2: E = I - B@X   (acc = 256*(B@X); split 3-product for nit >= NPRE)
// ---------------------------------------------------------------------------
__launch_bounds__(256)
__global__ void k_newton_e(unsigned char* __restrict__ wsb, int nit)
{
    const _Float16* Bhi = (const _Float16*)(wsb + OFF_BHI);
    const _Float16* Blo = (const _Float16*)(wsb + OFF_BLO);
    const _Float16* Xh  = (const _Float16*)(wsb + OFF_XHCM);
    const _Float16* Xl  = (const _Float16*)(wsb + OFF_XLCM);
    _Float16* Ecm = (_Float16*)(wsb + OFF_ECM);

    const int tid = threadIdx.x;
    const int lane = tid & 63, w = tid >> 6, q = lane >> 4, nI = lane & 15;
    const int bx = blockIdx.x;
    const int jt = bx & 7, R = (bx >> 3) * 16;
    const int c = jt * 64 + w * 16 + nI;

    __shared__ _Float16 pan[2][16 * LDSROW];
    #pragma unroll
    for (int rep = 0; rep < 4; ++rep) {
        int idx = tid + rep * 256; int row = idx >> 6, seg = idx & 63;
        *(f16x8*)&pan[0][row * LDSROW + seg * 8] = *(const f16x8*)&Bhi[(size_t)(R + row) * 512 + seg * 8];
        *(f16x8*)&pan[1][row * LDSROW + seg * 8] = *(const f16x8*)&Blo[(size_t)(R + row) * 512 + seg * 8];
    }
    __syncthreads();

    const _Float16* xh = Xh + (size_t)c * 512;
    const _Float16* xl = Xl + (size_t)c * 512;
    f32x4 acc = {0.f, 0.f, 0.f, 0.f};
    #pragma unroll
    for (int kk = 0; kk < 16; ++kk)
        acc = MF(*(f16x8*)&pan[0][nI * LDSROW + kk * 32 + q * 8], *(const f16x8*)&xh[kk * 32 + q * 8], acc);
    if (nit >= NPRE) {
        #pragma unroll
        for (int kk = 0; kk < 16; ++kk)
            acc = MF(*(f16x8*)&pan[0][nI * LDSROW + kk * 32 + q * 8], *(const f16x8*)&xl[kk * 32 + q * 8], acc);
        #pragma unroll
        for (int kk = 0; kk < 16; ++kk)
            acc = MF(*(f16x8*)&pan[1][nI * LDSROW + kk * 32 + q * 8], *(const f16x8*)&xh[kk * 32 + q * 8], acc);
    }
    f16x4 ev;
    #pragma unroll
    for (int r4 = 0; r4 < 4; ++r4) {
        int row = R + q * 4 + r4;
        float e = ((row == c) ? 1.f : 0.f) - acc[r4] * (1.f / 256.f);
        ev[r4] = (_Float16)(e * 32.f);
    }
    *(f16x4*)&Ecm[(size_t)c * 512 + R + q * 4] = ev;
}

// ---------------------------------------------------------------------------
// K3: X += X@E   (acc = (256X)@(32E) = 8192*(X@E)); fp32 master in Xf (cm).
// ---------------------------------------------------------------------------
__launch_bounds__(256)
__global__ void k_newton_u(unsigned char* __restrict__ wsb, int nit)
{
    const _Float16* Xrm_cur = (const _Float16*)(wsb + ((nit & 1) ? OFF_XRM1 : OFF_XRM0));
    _Float16*       Xrm_nxt = (_Float16*)(wsb + ((nit & 1) ? OFF_XRM0 : OFF_XRM1));
    const _Float16* Ecm = (const _Float16*)(wsb + OFF_ECM);
    float*    Xf = (float*)(wsb + OFF_XF);
    _Float16* Xh = (_Float16*)(wsb + OFF_XHCM);
    _Float16* Xl = (_Float16*)(wsb + OFF_XLCM);

    const int tid = threadIdx.x;
    const int lane = tid & 63, w = tid >> 6, q = lane >> 4, nI = lane & 15;
    const int bx = blockIdx.x;
    const int jt = bx & 7, R = (bx >> 3) * 16;
    const int c = jt * 64 + w * 16 + nI;

    __shared__ _Float16 pan[16 * LDSROW];
    #pragma unroll
    for (int rep = 0; rep < 4; ++rep) {
        int idx = tid + rep * 256; int row = idx >> 6, seg = idx & 63;
        *(f16x8*)&pan[row * LDSROW + seg * 8] = *(const f16x8*)&Xrm_cur[(size_t)(R + row) * 512 + seg * 8];
    }
    __syncthreads();

    const _Float16* ec = Ecm + (size_t)c * 512;
    f32x4 acc = {0.f, 0.f, 0.f, 0.f};
    #pragma unroll
    for (int kk = 0; kk < 16; ++kk)
        acc = MF(*(f16x8*)&pan[nI * LDSROW + kk * 32 + q * 8], *(const f16x8*)&ec[kk * 32 + q * 8], acc);

    f32x4 xv4 = *(f32x4*)&Xf[(size_t)c * 512 + R + q * 4];
    f16x4 h4, l4;
    #pragma unroll
    for (int r4 = 0; r4 < 4; ++r4) {
        float xv = xv4[r4] + acc[r4] * (1.f / 8192.f);
        xv4[r4] = xv;
        float sc = xv * 256.f;
        h4[r4] = (_Float16)sc;
        l4[r4] = (_Float16)(sc - (float)h4[r4]);
    }
    *(f32x4*)&Xf[(size_t)c * 512 + R + q * 4] = xv4;
    *(unsigned long long*)&Xh[(size_t)c * 512 + R + q * 4] = pack4(h4);
    *(unsigned long long*)&Xl[(size_t)c * 512 + R + q * 4] = pack4(l4);
    #pragma unroll
    for (int r4 = 0; r4 < 4; ++r4) {
        int row = R + q * 4 + r4;
        union { _Float16 h; unsigned short s; } cv; cv.h = h4[r4];
        unsigned x = cv.s;
        unsigned px = (unsigned)__shfl_xor((int)x, 1, 64);
        if ((nI & 1) == 0)
            *(unsigned*)&Xrm_nxt[(size_t)row * 512 + c] = x | (px << 16);
    }
}

// ---------------------------------------------------------------------------
// K4: G = I - M  ->  G buf0 as 256*G, hi/lo, row-major + col-major.
// ---------------------------------------------------------------------------
__launch_bounds__(256)
__global__ void k_gprep(unsigned char* __restrict__ wsb)
{
    const float* Xf = (const float*)(wsb + OFF_XF);
    _Float16* G = (_Float16*)(wsb + OFF_G0);
    _Float16* Grmh = G, *Grml = G + GSUB, *Gcmh = G + 2 * GSUB, *Gcml = G + 3 * GSUB;
    const int tid = threadIdx.x;
    const int C = blockIdx.x * 16;
    for (int idx = tid; idx < 8192; idx += 256) {
        int col = C + (idx >> 9), row = idx & 511;
        float g = ((row == col) ? 1.f : 0.f) - Xf[(size_t)col * 512 + row];
        float sc = g * 256.f;
        _Float16 h = (_Float16)sc;
        _Float16 l = (_Float16)(sc - (float)h);
        Gcmh[(size_t)col * 512 + row] = h;
        Gcml[(size_t)col * 512 + row] = l;
        Grmh[(size_t)row * 512 + col] = h;
        Grml[(size_t)row * 512 + col] = l;
    }
}

// ---------------------------------------------------------------------------
// K5: G2 = G@G (hi/lo split, 3 products). In: 256*G, out: 256*G^2.
// ---------------------------------------------------------------------------
__launch_bounds__(256)
__global__ void k_gsq(const _Float16* __restrict__ Gin, _Float16* __restrict__ Gout)
{
    const _Float16* rmh = Gin, *rml = Gin + GSUB, *cmh = Gin + 2 * GSUB, *cml = Gin + 3 * GSUB;
    _Float16* ormh = Gout; _Float16* orml = Gout + GSUB;
    _Float16* ocmh = Gout + 2 * GSUB; _Float16* ocml = Gout + 3 * GSUB;

    const int tid = threadIdx.x;
    const int lane = tid & 63, w = tid >> 6, q = lane >> 4, nI = lane & 15;
    const int bx = blockIdx.x;
    const int jt = bx & 7, R = (bx >> 3) * 16;
    const int c = jt * 64 + w * 16 + nI;

    __shared__ _Float16 pan[2][16 * LDSROW];
    #pragma unroll
    for (int rep = 0; rep < 4; ++rep) {
        int idx = tid + rep * 256; int row = idx >> 6, seg = idx & 63;
        *(f16x8*)&pan[0][row * LDSROW + seg * 8] = *(const f16x8*)&rmh[(size_t)(R + row) * 512 + seg * 8];
        *(f16x8*)&pan[1][row * LDSROW + seg * 8] = *(const f16x8*)&rml[(size_t)(R + row) * 512 + seg * 8];
    }
    __syncthreads();

    const _Float16* bh = cmh + (size_t)c * 512;
    const _Float16* bl = cml + (size_t)c * 512;
    f32x4 acc = {0.f, 0.f, 0.f, 0.f};
    #pragma unroll
    for (int kk = 0; kk < 16; ++kk) {
        f16x8 ah = *(f16x8*)&pan[0][nI * LDSROW + kk * 32 + q * 8];
        f16x8 al = *(f16x8*)&pan[1][nI * LDSROW + kk * 32 + q * 8];
        f16x8 vh = *(const f16x8*)&bh[kk * 32 + q * 8];
        f16x8 vl = *(const f16x8*)&bl[kk * 32 + q * 8];
        acc = MF(ah, vh, acc);
        acc = MF(ah, vl, acc);
        acc = MF(al, vh, acc);
    }
    f16x4 h4, l4;
    #pragma unroll
    for (int r4 = 0; r4 < 4; ++r4) {
        float v = acc[r4] * (1.f / 256.f);   // 256*G^2
        h4[r4] = (_Float16)v;
        l4[r4] = (_Float16)(v - (float)h4[r4]);
    }
    *(unsigned long long*)&ocmh[(size_t)c * 512 + R + q * 4] = pack4(h4);
    *(unsigned long long*)&ocml[(size_t)c * 512 + R + q * 4] = pack4(l4);
    #pragma unroll
    for (int r4 = 0; r4 < 4; ++r4) {
        int row = R + q * 4 + r4;
        union { _Float16 h; unsigned short s; } cv, cl; cv.h = h4[r4]; cl.h = l4[r4];
        unsigned xh = cv.s, xl = cl.s;
        unsigned pxh = (unsigned)__shfl_xor((int)xh, 1, 64);
        unsigned pxl = (unsigned)__shfl_xor((int)xl, 1, 64);
        if ((nI & 1) == 0) {
            *(unsigned*)&ormh[(size_t)row * 512 + c] = xh | (pxh << 16);
            *(unsigned*)&orml[(size_t)row * 512 + c] = xl | (pxl << 16);
        }
    }
}

// ---------------------------------------------------------------------------
// K6: phase-1 local chunk scan (8 steps, zero init), emit end state hi+lo.
// 256 blocks x 512 threads: bx = cg*128 + ch*8 + jt. a2 first-half held in
// registers (stream m2 only for kk>=8, plus m3): 24KB/wave-step from L2.
// ---------------------------------------------------------------------------
__launch_bounds__(512, 1)
__global__ void k_phase1(const float* __restrict__ xs, unsigned char* __restrict__ wsb)
{
    const _Float16* Mrm = (const _Float16*)(wsb + OFF_XRM1);   // NITER odd
    _Float16* sth = (_Float16*)(wsb + OFF_STH);
    _Float16* stl = (_Float16*)(wsb + OFF_STL);

    const int tid = threadIdx.x;
    const int lane = tid & 63, wv = tid >> 6, q = lane >> 4, nI = lane & 15;
    const int bx = blockIdx.x;
    const int cg = bx >> 7, ch = (bx >> 3) & 15, jt = bx & 7;
    const int rowbase = wv * 64;
    const int f0 = cg * 32 + nI;          // cf=1 adds +16

    __shared__ _Float16 Z[2][32 * ZROW];

    f16x8 a0[16], a1[16], a2r[8];
    #pragma unroll
    for (int kk = 0; kk < 16; ++kk)
        a0[kk] = *(const f16x8*)&Mrm[(size_t)(rowbase + nI) * 512 + kk * 32 + q * 8];
    #pragma unroll
    for (int kk = 0; kk < 16; ++kk)
        a1[kk] = *(const f16x8*)&Mrm[(size_t)(rowbase + 16 + nI) * 512 + kk * 32 + q * 8];
    #pragma unroll
    for (int kk = 0; kk < 8; ++kk)
        a2r[kk] = *(const f16x8*)&Mrm[(size_t)(rowbase + 32 + nI) * 512 + kk * 32 + q * 8];
    const _Float16* m2 = &Mrm[(size_t)(rowbase + 32 + nI) * 512];
    const _Float16* m3 = &Mrm[(size_t)(rowbase + 48 + nI) * 512];

    // acc[T][cf] = 256 * Y   (persistent across steps; MFMA C-in = C-out)
    f32x4 acc[4][2];
    #pragma unroll
    for (int T = 0; T < 4; ++T)
        #pragma unroll
        for (int cf = 0; cf < 2; ++cf)
            acc[T][cf] = (f32x4){0.f, 0.f, 0.f, 0.f};

    float xn[4][2][4];
    const int tg0 = ch * 8;

    {   // preamble: build Z[0] from x_0
        const size_t b0 = ((size_t)(jt * 128 + tg0) * 512) * 64 + f0;
        #pragma unroll
        for (int T = 0; T < 4; ++T)
            #pragma unroll
            for (int cf = 0; cf < 2; ++cf) {
                f16x4 zv;
                #pragma unroll
                for (int r4 = 0; r4 < 4; ++r4)
                    zv[r4] = (_Float16)xs[b0 + cf * 16 + (size_t)(rowbase + T * 16 + q * 4 + r4) * 64];
                *(f16x4*)&Z[0][(cf * 16 + nI) * ZROW + rowbase + T * 16 + q * 4] = zv;
            }
    }
    __syncthreads();

    for (int t = 0; t < 8; ++t) {
        if (t < 7) {
            const size_t bn = ((size_t)(jt * 128 + tg0 + t + 1) * 512) * 64 + f0;
            #pragma unroll
            for (int T = 0; T < 4; ++T)
                #pragma unroll
                for (int cf = 0; cf < 2; ++cf)
                    #pragma unroll
                    for (int r4 = 0; r4 < 4; ++r4)
                        xn[T][cf][r4] = xs[bn + cf * 16 + (size_t)(rowbase + T * 16 + q * 4 + r4) * 64];
        }

        const _Float16* zbA = &Z[t & 1][nI * ZROW];
        const _Float16* zbB = &Z[t & 1][(16 + nI) * ZROW];
        #pragma unroll
        for (int kk = 0; kk < 16; ++kk) {
            f16x8 bA = *(const f16x8*)&zbA[kk * 32 + q * 8];
            f16x8 bB = *(const f16x8*)&zbB[kk * 32 + q * 8];
            f16x8 v2 = (kk < 8) ? a2r[kk & 7] : *(const f16x8*)&m2[kk * 32 + q * 8];
            f16x8 v3 = *(const f16x8*)&m3[kk * 32 + q * 8];
            acc[0][0] = MF(a0[kk], bA, acc[0][0]);
            acc[0][1] = MF(a0[kk], bB, acc[0][1]);
            acc[1][0] = MF(a1[kk], bA, acc[1][0]);
            acc[1][1] = MF(a1[kk], bB, acc[1][1]);
            acc[2][0] = MF(v2,     bA, acc[2][0]);
            acc[2][1] = MF(v2,     bB, acc[2][1]);
            acc[3][0] = MF(v3,     bA, acc[3][0]);
            acc[3][1] = MF(v3,     bB, acc[3][1]);
        }

        if (t < 7) {
            #pragma unroll
            for (int T = 0; T < 4; ++T)
                #pragma unroll
                for (int cf = 0; cf < 2; ++cf) {
                    f16x4 zv;
                    #pragma unroll
                    for (int r4 = 0; r4 < 4; ++r4)
                        zv[r4] = (_Float16)(xn[T][cf][r4] - acc[T][cf][r4] * (1.f / 256.f));
                    *(f16x4*)&Z[(t + 1) & 1][(cf * 16 + nI) * ZROW + rowbase + T * 16 + q * 4] = zv;
                }
            __syncthreads();
        }
    }

    #pragma unroll
    for (int cf = 0; cf < 2; ++cf) {
        const size_t so = ((size_t)(ch * 8 + jt) * 64 + f0 + cf * 16) * 512;
        #pragma unroll
        for (int T = 0; T < 4; ++T) {
            f16x4 h4, l4;
            #pragma unroll
            for (int r4 = 0; r4 < 4; ++r4) {
                float y = acc[T][cf][r4] * (1.f / 256.f);
                h4[r4] = (_Float16)y;
                l4[r4] = (_Float16)(y - (float)h4[r4]);
            }
            *(unsigned long long*)&sth[so + rowbase + T * 16 + q * 4] = pack4(h4);
            *(unsigned long long*)&stl[so + rowbase + T * 16 + q * 4] = pack4(l4);
        }
    }
}

// ---------------------------------------------------------------------------
// K7: one carry hop: state[cch] = E_cch + G8 @ y_{cch-1}   (in place, hi/lo).
// 256 blocks x 512 threads: bx = rt*8 + jt; block = 16 out-rows x 64 f x jt.
// G8 row-panel (16 rows, hi+lo, 32KB) staged in LDS; 8 waves = 4 f-groups x
// 2 k-halves; k-halves reduced through LDS. ~160KB L2 stream per block.
// ---------------------------------------------------------------------------
__launch_bounds__(512, 1)
__global__ void k_hop(unsigned char* __restrict__ wsb, int cch)
{
    const _Float16* G8h = (const _Float16*)(wsb + OFF_G1);           // rm hi (256*G8)
    const _Float16* G8l = (const _Float16*)(wsb + OFF_G1) + GSUB;    // rm lo
    _Float16* sth = (_Float16*)(wsb + OFF_STH);
    _Float16* stl = (_Float16*)(wsb + OFF_STL);

    const int tid = threadIdx.x;
    const int lane = tid & 63, wv = tid >> 6, q = lane >> 4, nI = lane & 15;
    const int fg = wv & 3, kh = wv >> 2;
    const int bx = blockIdx.x;
    const int rt = bx >> 3, jt = bx & 7;
    const int R = rt * 16;

    __shared__ _Float16 LG[2][16 * GROW];
    __shared__ float red[4][16][20];

    // stage G8 rows R..R+16 (hi and lo) into LDS: 2048 x 16B chunks
    #pragma unroll
    for (int rep = 0; rep < 4; ++rep) {
        int idx = tid + rep * 512;
        int buf = idx >> 10, rs = idx & 1023;
        int row = rs >> 6, seg = rs & 63;
        const _Float16* src = buf ? G8l : G8h;
        *(f16x8*)&LG[buf][row * GROW + seg * 8] = *(const f16x8*)&src[(size_t)(R + row) * 512 + seg * 8];
    }
    __syncthreads();

    // B operands: y_{cch-1} hi/lo, this wave's f-column and k-half
    const size_t ypo = ((size_t)((cch - 1) * 8 + jt) * 64 + fg * 16 + nI) * 512 + kh * 256;
    const _Float16* yh = sth + ypo;
    const _Float16* yl = stl + ypo;

    f32x4 acc = {0.f, 0.f, 0.f, 0.f};
    #pragma unroll
    for (int kk = 0; kk < 8; ++kk) {
        f16x8 bh = *(const f16x8*)&yh[kk * 32 + q * 8];
        f16x8 bl = *(const f16x8*)&yl[kk * 32 + q * 8];
        f16x8 ah = *(const f16x8*)&LG[0][nI * GROW + kh * 256 + kk * 32 + q * 8];
        f16x8 al = *(const f16x8*)&LG[1][nI * GROW + kh * 256 + kk * 32 + q * 8];
        acc = MF(ah, bh, acc);
        acc = MF(ah, bl, acc);
        acc = MF(al, bh, acc);
    }

    if (kh == 0) {
        #pragma unroll
        for (int r4 = 0; r4 < 4; ++r4)
            red[fg][nI][q * 4 + r4] = acc[r4];
    }
    __syncthreads();
    if (kh == 1) {
        const size_t sco = ((size_t)(cch * 8 + jt) * 64 + fg * 16 + nI) * 512 + R + q * 4;
        f16x4 eh = *(const f16x4*)&sth[sco];
        f16x4 el = *(const f16x4*)&stl[sco];
        f16x4 h4, l4;
        #pragma unroll
        for (int r4 = 0; r4 < 4; ++r4) {
            float y = (float)eh[r4] + (float)el[r4]
                    + (acc[r4] + red[fg][nI][q * 4 + r4]) * (1.f / 256.f);
            h4[r4] = (_Float16)y;
            l4[r4] = (_Float16)(y - (float)h4[r4]);
        }
        *(unsigned long long*)&sth[sco] = pack4(h4);
        *(unsigned long long*)&stl[sco] = pack4(l4);
    }
}

// ---------------------------------------------------------------------------
// K8: phase-2 final chunk scan (8 steps) with hi+lo carry-in; writes out (nt).
// Same a2-half register hold as K6.
// ---------------------------------------------------------------------------
__launch_bounds__(512, 1)
__global__ void k_phase2(const float* __restrict__ xs, unsigned char* __restrict__ wsb,
                         float* __restrict__ out)
{
    const _Float16* Mrm = (const _Float16*)(wsb + OFF_XRM1);
    const _Float16* sth = (const _Float16*)(wsb + OFF_STH);
    const _Float16* stl = (const _Float16*)(wsb + OFF_STL);

    const int tid = threadIdx.x;
    const int lane = tid & 63, wv = tid >> 6, q = lane >> 4, nI = lane & 15;
    const int bx = blockIdx.x;
    const int cg = bx >> 7, ch = (bx >> 3) & 15, jt = bx & 7;
    const int rowbase = wv * 64;
    const int f0 = cg * 32 + nI;

    __shared__ _Float16 Z[2][32 * ZROW];

    f16x8 a0[16], a1[16], a2r[8];
    #pragma unroll
    for (int kk = 0; kk < 16; ++kk)
        a0[kk] = *(const f16x8*)&Mrm[(size_t)(rowbase + nI) * 512 + kk * 32 + q * 8];
    #pragma unroll
    for (int kk = 0; kk < 16; ++kk)
        a1[kk] = *(const f16x8*)&Mrm[(size_t)(rowbase + 16 + nI) * 512 + kk * 32 + q * 8];
    #pragma unroll
    for (int kk = 0; kk < 8; ++kk)
        a2r[kk] = *(const f16x8*)&Mrm[(size_t)(rowbase + 32 + nI) * 512 + kk * 32 + q * 8];
    const _Float16* m2 = &Mrm[(size_t)(rowbase + 32 + nI) * 512];
    const _Float16* m3 = &Mrm[(size_t)(rowbase + 48 + nI) * 512];

    // acc = 256 * Y, initialized from hi+lo carry state (or 0 for chunk 0)
    f32x4 acc[4][2];
    if (ch == 0) {
        #pragma unroll
        for (int T = 0; T < 4; ++T)
            #pragma unroll
            for (int cf = 0; cf < 2; ++cf)
                acc[T][cf] = (f32x4){0.f, 0.f, 0.f, 0.f};
    } else {
        #pragma unroll
        for (int cf = 0; cf < 2; ++cf) {
            const size_t so = ((size_t)((ch - 1) * 8 + jt) * 64 + f0 + cf * 16) * 512;
            #pragma unroll
            for (int T = 0; T < 4; ++T) {
                f16x4 svh = *(const f16x4*)&sth[so + rowbase + T * 16 + q * 4];
                f16x4 svl = *(const f16x4*)&stl[so + rowbase + T * 16 + q * 4];
                #pragma unroll
                for (int r4 = 0; r4 < 4; ++r4)
                    acc[T][cf][r4] = 256.f * ((float)svh[r4] + (float)svl[r4]);
            }
        }
    }

    float xn[4][2][4];
    const int tg0 = ch * 8;
    {   // preamble: Z[0] = x_0 - Y_carry
        const size_t b0 = ((size_t)(jt * 128 + tg0) * 512) * 64 + f0;
        #pragma unroll
        for (int T = 0; T < 4; ++T)
            #pragma unroll
            for (int cf = 0; cf < 2; ++cf) {
                f16x4 zv;
                #pragma unroll
                for (int r4 = 0; r4 < 4; ++r4) {
                    float xv = xs[b0 + cf * 16 + (size_t)(rowbase + T * 16 + q * 4 + r4) * 64];
                    zv[r4] = (_Float16)(xv - acc[T][cf][r4] * (1.f / 256.f));
                }
                *(f16x4*)&Z[0][(cf * 16 + nI) * ZROW + rowbase + T * 16 + q * 4] = zv;
            }
    }
    __syncthreads();

    for (int t = 0; t < 8; ++t) {
        if (t < 7) {
            const size_t bn = ((size_t)(jt * 128 + tg0 + t + 1) * 512) * 64 + f0;
            #pragma unroll
            for (int T = 0; T < 4; ++T)
                #pragma unroll
                for (int cf = 0; cf < 2; ++cf)
                    #pragma unroll
                    for (int r4 = 0; r4 < 4; ++r4)
                        xn[T][cf][r4] = xs[bn + cf * 16 + (size_t)(rowbase + T * 16 + q * 4 + r4) * 64];
        }

        const _Float16* zbA = &Z[t & 1][nI * ZROW];
        const _Float16* zbB = &Z[t & 1][(16 + nI) * ZROW];
        #pragma unroll
        for (int kk = 0; kk < 16; ++kk) {
            f16x8 bA = *(const f16x8*)&zbA[kk * 32 + q * 8];
            f16x8 bB = *(const f16x8*)&zbB[kk * 32 + q * 8];
            f16x8 v2 = (kk < 8) ? a2r[kk & 7] : *(const f16x8*)&m2[kk * 32 + q * 8];
            f16x8 v3 = *(const f16x8*)&m3[kk * 32 + q * 8];
            acc[0][0] = MF(a0[kk], bA, acc[0][0]);
            acc[0][1] = MF(a0[kk], bB, acc[0][1]);
            acc[1][0] = MF(a1[kk], bA, acc[1][0]);
            acc[1][1] = MF(a1[kk], bB, acc[1][1]);
            acc[2][0] = MF(v2,     bA, acc[2][0]);
            acc[2][1] = MF(v2,     bB, acc[2][1]);
            acc[3][0] = MF(v3,     bA, acc[3][0]);
            acc[3][1] = MF(v3,     bB, acc[3][1]);
        }

        const size_t base = ((size_t)(jt * 128 + tg0 + t) * 512) * 64 + f0;
        #pragma unroll
        for (int T = 0; T < 4; ++T)
            #pragma unroll
            for (int cf = 0; cf < 2; ++cf)
                #pragma unroll
                for (int r4 = 0; r4 < 4; ++r4)
                    __builtin_nontemporal_store(acc[T][cf][r4] * (1.f / 256.f),
                        &out[base + cf * 16 + (size_t)(rowbase + T * 16 + q * 4 + r4) * 64]);

        if (t < 7) {
            #pragma unroll
            for (int T = 0; T < 4; ++T)
                #pragma unroll
                for (int cf = 0; cf < 2; ++cf) {
                    f16x4 zv;
                    #pragma unroll
                    for (int r4 = 0; r4 < 4; ++r4)
                        zv[r4] = (_Float16)(xn[T][cf][r4] - acc[T][cf][r4] * (1.f / 256.f));
                    *(f16x4*)&Z[(t + 1) & 1][(cf * 16 + nI) * ZROW + rowbase + T * 16 + q * 4] = zv;
                }
            __syncthreads();
        }
    }
}

extern "C" void kernel_launch(void* const* d_in, const int* in_sizes, int n_in,
                              void* d_out, int out_size, void* d_ws, size_t ws_size,
                              hipStream_t stream)
{
    const float* xs = (const float*)d_in[0];   // [8,128,512,64] fp32
    const float* A  = (const float*)d_in[1];   // [1,512,512] fp32
    float* out = (float*)d_out;                // [8,128,512,64] fp32
    unsigned char* ws = (unsigned char*)d_ws;  // ~25.7 MB used

    k_prep_rows<<<dim3(32), dim3(256), 0, stream>>>(A, ws);
    k_init_x<<<dim3(32), dim3(256), 0, stream>>>(ws);

    for (int nit = 0; nit < NITER; ++nit) {
        k_newton_e<<<dim3(256), dim3(256), 0, stream>>>(ws, nit);
        k_newton_u<<<dim3(256), dim3(256), 0, stream>>>(ws, nit);
    }

    k_gprep<<<dim3(32), dim3(256), 0, stream>>>(ws);
    _Float16* G0 = (_Float16*)(ws + OFF_G0);
    _Float16* G1 = (_Float16*)(ws + OFF_G1);
    k_gsq<<<dim3(256), dim3(256), 0, stream>>>(G0, G1);   // G^2 -> buf1
    k_gsq<<<dim3(256), dim3(256), 0, stream>>>(G1, G0);   // G^4 -> buf0
    k_gsq<<<dim3(256), dim3(256), 0, stream>>>(G0, G1);   // G^8 -> buf1

    k_phase1<<<dim3(256), dim3(512), 0, stream>>>(xs, ws);
    for (int c = 1; c <= 14; ++c)
        k_hop<<<dim3(256), dim3(512), 0, stream>>>(ws, c);
    k_phase2<<<dim3(256), dim3(512), 0, stream>>>(xs, ws, out);
}